// Round 1
// baseline (274.189 us; speedup 1.0000x reference)
//
#include <hip/hip_runtime.h>

#define SEQ  2048
#define DIM  1024
#define NTOK 8192   // 4*SEQ
#define NQKV 3072

typedef __attribute__((ext_vector_type(8))) __bf16 bf16x8;
typedef __attribute__((ext_vector_type(4))) float  f32x4;

__device__ __forceinline__ unsigned short f2bf(float f) {
    unsigned int u = __float_as_uint(f);
    u += 0x7fffu + ((u >> 16) & 1u);          // round-to-nearest-even
    return (unsigned short)(u >> 16);
}

__device__ __forceinline__ float bfu2f(unsigned int lo16) {
    return __uint_as_float(lo16 << 16);
}

__device__ __forceinline__ void load_lds_128(const unsigned short* g, unsigned short* l) {
    __builtin_amdgcn_global_load_lds(
        (const __attribute__((address_space(1))) void*)g,
        (__attribute__((address_space(3))) void*)l, 16, 0, 0);
}

// ---------------------------------------------------------------------------
// NT GEMM, bf16 MFMA 16x16x32, 256xBN block, BK=32, 8 waves (2M x 4N),
// 4-deep K-tile LDS pipeline with counted vmcnt (T3+T4) + setprio (T5).
//
// LDS: A tiles [256][32] bf16 (16KB), B tiles [BN][32] (BN/4 KB), x4 buffers.
// 64-byte rows make the 16x16x32 fragment ds_read_b128 bank-conflict-free
// (row stride = half the bank period; chunks tile the rest) -> no swizzle,
// global_load_lds stays linear on both sides.
//
// Schedule per K-tile t (NF=4: two phases; NF=2: one phase):
//   {ds_read frags | issue global_load_lds for tile t+3 | barrier |
//    lgkmcnt(0) | setprio(1) | 16 MFMA | setprio(0) | [vmcnt(2L)] | barrier}
// vmcnt(2L) only at tile end: tiles t+2,t+3 (2L loads) stay in flight; tile
// t+1 (needed by next phase's ds_reads) is guaranteed drained.  WAR: tile t
// stages buffer (t+3)&3 == (t-1)&3, whose last ds_read drained at t-1's
// final lgkmcnt(0) before the barrier this stage issues behind.
//
// MODE 0: fused QKV epilogue (q,k bf16 + bias; v transposed into vt + bias)
// MODE 1: fp32 C = acc * inv_rs[row]   (normalized P.V output)
// MODE 2: bf16 C = exp(acc * alpha)    (unnormalized softmax numerator)
// ---------------------------------------------------------------------------
template <int MODE, int NF>   // NF = per-wave N-frags; BN = NF*64
__global__ __launch_bounds__(512, 2)
void gemm256(const unsigned short* __restrict__ A, const unsigned short* __restrict__ B,
             void* __restrict__ Cv,
             const float* __restrict__ b0, const float* __restrict__ b1,
             const float* __restrict__ b2, unsigned short* __restrict__ vt,
             const float* __restrict__ inv_rs,
             int K, int lda, int ldb, int ldc,
             long sA, long sB, long sC, float alpha)
{
    constexpr int BN  = NF * 64;
    constexpr int AT  = 256 * 32;              // elems per A-tile buffer (16 KB)
    constexpr int BT  = BN * 32;               // elems per B-tile buffer
    constexpr int LPT = 2 + BN / 128;          // loads/thread/tile: A:2 + B:(2|1)

    __shared__ unsigned short As[4 * AT];      // 64 KB
    __shared__ unsigned short Bs[4 * BT];      // 64 KB (NF=4) / 32 KB (NF=2)

    const int tid  = threadIdx.x;              // 512 threads = 8 waves
    const int wave = tid >> 6;
    const int lane = tid & 63;
    const int l4   = lane & 15;
    const int lh   = lane >> 4;
    const int wm   = wave >> 2;                // 0..1  (M half)
    const int wn   = wave & 3;                 // 0..3  (N quarter)

    const int m0 = blockIdx.x * 256;
    const int n0 = blockIdx.y * BN;
    const int z  = blockIdx.z;
    A += (long)z * sA;
    B += (long)z * sB;

    // ---- staging map: chunk ch = tid (+512) -> row ch>>2, 16B col ch&3 ----
    const unsigned short* Ag0 = A + (long)(m0 + (tid >> 2)) * lda + (tid & 3) * 8;
    const unsigned short* Ag1 = Ag0 + (long)128 * lda;
    const unsigned short* Bg0 = B + (long)(n0 + (tid >> 2)) * ldb + (tid & 3) * 8;
    const unsigned short* Bg1 = Bg0 + (long)128 * ldb;   // NF==4 only
    unsigned short* Al0 = As + tid * 8;
    unsigned short* Bl0 = Bs + tid * 8;

    const int NT = K >> 5;                     // K-tiles of 32

    auto stageA = [&](int t) {
        const int bo = (t & 3) * AT;
        load_lds_128(Ag0 + (long)t * 32, Al0 + bo);
        load_lds_128(Ag1 + (long)t * 32, Al0 + bo + 4096);
    };
    auto stageB = [&](int t) {
        const int bo = (t & 3) * BT;
        load_lds_128(Bg0 + (long)t * 32, Bl0 + bo);
        if constexpr (NF == 4)
            load_lds_128(Bg1 + (long)t * 32, Bl0 + bo + 4096);
    };

    // ---- fragment LDS element offsets (within one tile buffer) ----
    // A frag mf: row = wm*128 + mf*16 + (lane&15), k = (lane>>4)*8
    // B frag nf: row = wn*(BN/4) + nf*16 + (lane&15), k = (lane>>4)*8
    const int aoff = (wm * 128 + l4) * 32 + lh * 8;        // + mf*512 + bi*AT
    const int boff = (wn * (BN / 4) + l4) * 32 + lh * 8;   // + nf*512 + bi*BT

    f32x4 acc[8][NF] = {};

    // ---- prologue: stage tiles 0..2, drain tile 0 (2 tiles stay in flight) ----
    stageA(0); stageB(0);
    stageA(1); stageB(1);
    stageA(2); stageB(2);
    asm volatile("s_waitcnt vmcnt(%0)" :: "n"(2 * LPT) : "memory");
    __builtin_amdgcn_s_barrier();

    for (int t = 0; t < NT; ++t) {
        const int bi = t & 3;
        const unsigned short* Ab = As + bi * AT + aoff;
        const unsigned short* Bb = Bs + bi * BT + boff;
        bf16x8 b[NF];

        if constexpr (NF == 4) {
            bf16x8 a[4];
            // ---------- phase 1: B all + A m0..3, stage A(t+3) ----------
#pragma unroll
            for (int nf = 0; nf < 4; ++nf) b[nf] = *(const bf16x8*)(Bb + nf * 512);
#pragma unroll
            for (int mf = 0; mf < 4; ++mf) a[mf] = *(const bf16x8*)(Ab + mf * 512);
            if (t + 3 < NT) stageA(t + 3);
            __builtin_amdgcn_s_barrier();
            asm volatile("s_waitcnt lgkmcnt(0)" ::: "memory");
            __builtin_amdgcn_sched_barrier(0);
            __builtin_amdgcn_s_setprio(1);
#pragma unroll
            for (int mf = 0; mf < 4; ++mf)
#pragma unroll
                for (int nf = 0; nf < 4; ++nf)
                    acc[mf][nf] = __builtin_amdgcn_mfma_f32_16x16x32_bf16(
                        a[mf], b[nf], acc[mf][nf], 0, 0, 0);
            __builtin_amdgcn_s_setprio(0);
            __builtin_amdgcn_s_barrier();
            // ---------- phase 2: A m4..7, stage B(t+3), tile-end vmcnt ----------
#pragma unroll
            for (int mf = 0; mf < 4; ++mf) a[mf] = *(const bf16x8*)(Ab + (mf + 4) * 512);
            if (t + 3 < NT) stageB(t + 3);
            __builtin_amdgcn_s_barrier();
            asm volatile("s_waitcnt lgkmcnt(0)" ::: "memory");
            __builtin_amdgcn_sched_barrier(0);
            __builtin_amdgcn_s_setprio(1);
#pragma unroll
            for (int mf = 0; mf < 4; ++mf)
#pragma unroll
                for (int nf = 0; nf < 4; ++nf)
                    acc[mf + 4][nf] = __builtin_amdgcn_mfma_f32_16x16x32_bf16(
                        a[mf], b[nf], acc[mf + 4][nf], 0, 0, 0);
            __builtin_amdgcn_s_setprio(0);
            asm volatile("s_waitcnt vmcnt(%0)" :: "n"(2 * LPT) : "memory");
            __builtin_amdgcn_s_barrier();
        } else {
            bf16x8 a8[8];
            // ---------- single phase: B + A m0..7, stage A+B(t+3) ----------
#pragma unroll
            for (int nf = 0; nf < NF; ++nf) b[nf] = *(const bf16x8*)(Bb + nf * 512);
#pragma unroll
            for (int mf = 0; mf < 8; ++mf) a8[mf] = *(const bf16x8*)(Ab + mf * 512);
            if (t + 3 < NT) { stageA(t + 3); stageB(t + 3); }
            __builtin_amdgcn_s_barrier();
            asm volatile("s_waitcnt lgkmcnt(0)" ::: "memory");
            __builtin_amdgcn_sched_barrier(0);
            __builtin_amdgcn_s_setprio(1);
#pragma unroll
            for (int mf = 0; mf < 8; ++mf)
#pragma unroll
                for (int nf = 0; nf < NF; ++nf)
                    acc[mf][nf] = __builtin_amdgcn_mfma_f32_16x16x32_bf16(
                        a8[mf], b[nf], acc[mf][nf], 0, 0, 0);
            __builtin_amdgcn_s_setprio(0);
            asm volatile("s_waitcnt vmcnt(%0)" :: "n"(2 * LPT) : "memory");
            __builtin_amdgcn_s_barrier();
        }
    }

    // ---- epilogue ----
    // C/D 16x16x32: col = lane&15, row = (lane>>4)*4 + reg  [m89/m91]
    const int r0 = m0 + wm * 128 + lh * 4;          // + mf*16 + reg
    const int c0 = n0 + wn * (BN / 4) + l4;         // + nf*16

    if (MODE == 0) {
        if (n0 >= 2048) {
            // V columns -> vt[b][d][m] (+bias), packed 4-m ushort4 stores
#pragma unroll
            for (int nf = 0; nf < NF; ++nf) {
                const int d = c0 + nf * 16 - 2048;
                const float bias = b2[d];
#pragma unroll
                for (int mf = 0; mf < 8; ++mf) {
                    const int row = r0 + mf * 16;
                    const int bb = row >> 11;
                    const int mm = row & 2047;
                    ushort4 u;
                    u.x = f2bf(acc[mf][nf][0] + bias);
                    u.y = f2bf(acc[mf][nf][1] + bias);
                    u.z = f2bf(acc[mf][nf][2] + bias);
                    u.w = f2bf(acc[mf][nf][3] + bias);
                    *(ushort4*)(vt + ((long)bb * DIM + d) * SEQ + mm) = u;
                }
            }
        } else {
            unsigned short* C16 = (unsigned short*)Cv;
#pragma unroll
            for (int nf = 0; nf < NF; ++nf) {
                const int col = c0 + nf * 16;
                const float bias = (col >= 1024) ? b1[col - 1024] : b0[col];
#pragma unroll
                for (int mf = 0; mf < 8; ++mf)
#pragma unroll
                    for (int r = 0; r < 4; ++r)
                        C16[(long)(r0 + mf * 16 + r) * ldc + col] =
                            f2bf(acc[mf][nf][r] + bias);
            }
        }
    } else if (MODE == 1) {
        float* C = (float*)Cv + (long)z * sC;
        const float* ir = inv_rs + (long)z * SEQ;
#pragma unroll
        for (int mf = 0; mf < 8; ++mf) {
            const int row = r0 + mf * 16;
            const float4 inv4 = *(const float4*)(ir + row);
#pragma unroll
            for (int nf = 0; nf < NF; ++nf) {
                const int col = c0 + nf * 16;
                C[(long)(row + 0) * ldc + col] = acc[mf][nf][0] * inv4.x;
                C[(long)(row + 1) * ldc + col] = acc[mf][nf][1] * inv4.y;
                C[(long)(row + 2) * ldc + col] = acc[mf][nf][2] * inv4.z;
                C[(long)(row + 3) * ldc + col] = acc[mf][nf][3] * inv4.w;
            }
        }
    } else {  // MODE 2: P = exp(acc * alpha), bf16, unnormalized
        unsigned short* C16 = (unsigned short*)Cv + (long)z * sC;
#pragma unroll
        for (int nf = 0; nf < NF; ++nf) {
            const int col = c0 + nf * 16;
#pragma unroll
            for (int mf = 0; mf < 8; ++mf)
#pragma unroll
                for (int r = 0; r < 4; ++r)
                    C16[(long)(r0 + mf * 16 + r) * ldc + col] =
                        f2bf(__expf(acc[mf][nf][r] * alpha));
        }
    }
}

// ---------------------------------------------------------------------------
__global__ __launch_bounds__(256)
void cvt_x(const float* __restrict__ src, unsigned short* __restrict__ dst, int n4)
{
    int i = blockIdx.x * 256 + threadIdx.x;
    if (i < n4) {
        float4 f = ((const float4*)src)[i];
        ushort4 u;
        u.x = f2bf(f.x); u.y = f2bf(f.y); u.z = f2bf(f.z); u.w = f2bf(f.w);
        ((ushort4*)dst)[i] = u;
    }
}

__global__ __launch_bounds__(256)
void cvt_w3(const float* __restrict__ Wq, const float* __restrict__ Wk,
            const float* __restrict__ Wv, unsigned short* __restrict__ dst)
{
    const int sel = blockIdx.y;
    const float* src = (sel == 0) ? Wq : ((sel == 1) ? Wk : Wv);
    const int i = blockIdx.x * 256 + threadIdx.x;
    float4 f = ((const float4*)src)[i];
    ushort4 u;
    u.x = f2bf(f.x); u.y = f2bf(f.y); u.z = f2bf(f.z); u.w = f2bf(f.w);
    ((ushort4*)(dst + (long)sel * DIM * DIM))[i] = u;
}

// ---------------------------------------------------------------------------
// inv_rs[row] = 1 / sum(P[row][:]) over 2048 bf16 values. 1 wave per row.
// ---------------------------------------------------------------------------
__global__ __launch_bounds__(256)
void rowsum_inv(const unsigned short* __restrict__ P, float* __restrict__ inv_rs)
{
    const int row  = blockIdx.x * 4 + (threadIdx.x >> 6);
    const int lane = threadIdx.x & 63;
    const unsigned short* pr = P + (long)row * SEQ;

    float s = 0.f;
#pragma unroll
    for (int it = 0; it < 4; ++it) {
        uint4 u = *(const uint4*)(pr + (it * 64 + lane) * 8);
        s += bfu2f(u.x & 0xffffu) + __uint_as_float(u.x & 0xffff0000u);
        s += bfu2f(u.y & 0xffffu) + __uint_as_float(u.y & 0xffff0000u);
        s += bfu2f(u.z & 0xffffu) + __uint_as_float(u.z & 0xffff0000u);
        s += bfu2f(u.w & 0xffffu) + __uint_as_float(u.w & 0xffff0000u);
    }
    for (int off = 32; off > 0; off >>= 1)
        s += __shfl_xor(s, off);
    if (lane == 0) inv_rs[row] = 1.0f / s;
}

// ---------------------------------------------------------------------------
extern "C" void kernel_launch(void* const* d_in, const int* in_sizes, int n_in,
                              void* d_out, int out_size, void* d_ws, size_t ws_size,
                              hipStream_t stream)
{
    const float* x  = (const float*)d_in[0];
    const float* Wq = (const float*)d_in[1];
    const float* bq = (const float*)d_in[2];
    const float* Wk = (const float*)d_in[3];
    const float* bk = (const float*)d_in[4];
    const float* Wv = (const float*)d_in[5];
    const float* bv = (const float*)d_in[6];
    float* out = (float*)d_out;

    // Workspace layout (same as previous round, >=160MB + 32KB):
    //  [0,16MB):    xb bf16 [8192][1024]
    //  [16,22MB):   Wb bf16 [3][1024][1024]
    //  [64,112MB):  qkv bf16 [8192][3072]  (V cols never written; vt instead)
    //  [112,128MB): vt  bf16 [4][1024][2048]
    //  [128,160MB): P   bf16 [4][2048][2048]  (unnormalized exp)
    //  [160MB,+32KB): inv_rs fp32 [8192]
    char* ws = (char*)d_ws;
    unsigned short* xb   = (unsigned short*)ws;
    unsigned short* Wb   = (unsigned short*)(ws + 16u * 1024 * 1024);
    unsigned short* qkv  = (unsigned short*)(ws + 64u * 1024 * 1024);
    unsigned short* vt   = (unsigned short*)(ws + 112u * 1024 * 1024);
    unsigned short* P    = (unsigned short*)(ws + 128u * 1024 * 1024);
    float*          irs  = (float*)(ws + 160u * 1024 * 1024);

    const float scale = 0.03125f;   // 1/sqrt(1024)
    dim3 blk(256);
    dim3 blk512(512);

    // 1) converts
    cvt_x<<<NTOK * DIM / 4 / 256, blk, 0, stream>>>(x, xb, NTOK * DIM / 4);
    cvt_w3<<<dim3(DIM * DIM / 4 / 256, 3), blk, 0, stream>>>(Wq, Wk, Wv, Wb);

    // 2) fused QKV projection, 256x128 tiles -> 32*24 = 768 blocks (3/CU exact)
    gemm256<0, 2><<<dim3(NTOK / 256, NQKV / 128), blk512, 0, stream>>>(
        xb, Wb, qkv, bq, bk, bv, vt, nullptr,
        DIM, DIM, DIM, NQKV, 0, 0, 0, 1.0f);

    // 3) P[b] = exp(q[b].k[b]^T * scale), 256x256 tiles -> 8*8*4 = 256 blocks
    gemm256<2, 4><<<dim3(SEQ / 256, SEQ / 256, 4), blk512, 0, stream>>>(
        qkv, qkv + 1024, P, nullptr, nullptr, nullptr, nullptr, nullptr,
        DIM, NQKV, NQKV, SEQ,
        (long)SEQ * NQKV, (long)SEQ * NQKV, (long)SEQ * SEQ, scale);

    // 4) inv_rs = 1 / rowsum(P)
    rowsum_inv<<<NTOK / 4, blk, 0, stream>>>(P, irs);

    // 5) out[b] = (P[b].vt[b]^T) * inv_rs, 256x128 tiles -> 8*8*4 = 256 blocks
    gemm256<1, 2><<<dim3(SEQ / 256, DIM / 128, 4), blk512, 0, stream>>>(
        P, vt, out, nullptr, nullptr, nullptr, nullptr, irs,
        SEQ, SEQ, SEQ, DIM,
        (long)SEQ * SEQ, (long)DIM * SEQ, (long)SEQ * DIM, 1.0f);
}

// Round 2
// 255.938 us; speedup vs baseline: 1.0713x; 1.0713x over previous
//
#include <hip/hip_runtime.h>

#define SEQ  2048
#define DIM  1024
#define NTOK 8192   // 4*SEQ
#define NQKV 3072

typedef __attribute__((ext_vector_type(8))) __bf16 bf16x8;
typedef __attribute__((ext_vector_type(4))) float  f32x4;

__device__ __forceinline__ unsigned short f2bf(float f) {
    unsigned int u = __float_as_uint(f);
    u += 0x7fffu + ((u >> 16) & 1u);          // round-to-nearest-even
    return (unsigned short)(u >> 16);
}

__device__ __forceinline__ float bfu2f(unsigned int lo16) {
    return __uint_as_float(lo16 << 16);
}

__device__ __forceinline__ void load_lds_128(const unsigned short* g, unsigned short* l) {
    __builtin_amdgcn_global_load_lds(
        (const __attribute__((address_space(1))) void*)g,
        (__attribute__((address_space(3))) void*)l, 16, 0, 0);
}

#define BAR()    asm volatile("s_barrier" ::: "memory")
#define WAITL0() do { asm volatile("s_waitcnt lgkmcnt(0)" ::: "memory"); \
                      __builtin_amdgcn_sched_barrier(0); } while (0)

// ---------------------------------------------------------------------------
// NT GEMM, bf16 MFMA 16x16x32. 256x128 block, BK=64, 8 waves as 4M x 2N
// (64x64 per wave, acc[4][4]).  3-slot LDS ring, distance-2 prefetch,
// counted vmcnt(6) at tile end (never 0 in steady state).
//
// LDS rows are 128B (full bank period).  Chunk slot c of row r holds global
// 16B-chunk g = c ^ (r&7)  -> 16-row fragment ds_read_b128 is 2-way (free).
// global_load_lds dest stays linear; the XOR is applied to the per-lane
// GLOBAL source address (same involution on store and read).
//
// Per K-tile: 2 phases (kk=0,1), each:
//   { 8 x ds_read_b128 | 3 x global_load_lds (tile t+2) | s_barrier |
//     lgkmcnt(0)+sched_barrier | setprio(1) | 16 MFMA | setprio(0) }
// tile end: vmcnt(6) [tile t+2's 6 loads stay in flight] + s_barrier.
// WAR: stage at iter t writes slot (t+2)%3 == (t-1)%3, whose last ds_reads
// drained at t-1's lgkmcnt(0), >=2 barriers before the stage issues.
//
// MODE 0: fused QKV epilogue (q,k bf16 + bias; v transposed into vt + bias)
// MODE 1: fp32 C = acc * inv_rs[row]   (normalized P.V output)
// MODE 2: bf16 C = exp(acc * alpha)    (unnormalized softmax numerator)
// ---------------------------------------------------------------------------
template <int MODE>
__global__ __launch_bounds__(512, 2)
void gemm256(const unsigned short* __restrict__ A, const unsigned short* __restrict__ B,
             void* __restrict__ Cv,
             const float* __restrict__ b0, const float* __restrict__ b1,
             const float* __restrict__ b2, unsigned short* __restrict__ vt,
             const float* __restrict__ inv_rs,
             int K, int lda, int ldb, int ldc,
             long sA, long sB, long sC, float alpha)
{
    constexpr int AT = 256 * 64;               // elems per A slot (32 KB)
    constexpr int BT = 128 * 64;               // elems per B slot (16 KB)
    __shared__ __align__(16) unsigned short As[3 * AT];   // 96 KB
    __shared__ __align__(16) unsigned short Bs[3 * BT];   // 48 KB

    const int tid  = threadIdx.x;              // 512 threads = 8 waves
    const int wave = tid >> 6;
    const int lane = tid & 63;
    const int l4   = lane & 15;
    const int lh   = lane >> 4;
    const int wm   = wave >> 1;                // 0..3  (M quarter)
    const int wn   = wave & 1;                 // 0..1  (N half)

    const int m0 = blockIdx.x * 256;
    const int n0 = blockIdx.y * 128;
    const int z  = blockIdx.z;
    A += (long)z * sA;
    B += (long)z * sB;

    // ---- staging map: LDS linear pos s = tid + 512p -> row s>>3, slot s&7.
    // slot c holds global chunk g = c ^ (r&7); g is p-invariant (64p%8==0).
    const int r0 = tid >> 3;                   // 0..63
    const int gc = (tid & 7) ^ (r0 & 7);
    const unsigned short* Ag = A + (long)(m0 + r0) * lda + gc * 8;
    const unsigned short* Bg = B + (long)(n0 + r0) * ldb + gc * 8;
    unsigned short* Al = As + tid * 8;
    unsigned short* Bl = Bs + tid * 8;

    const int NT = K >> 6;                     // K-tiles of 64

    // phase 0: A rows 0-127 + B rows 0-63;  phase 1: A rows 128-255 + B 64-127
    auto stage = [&](int t, int slot, int ph) {
        const long kof = (long)t * 64;
        unsigned short* al = Al + slot * AT;
        unsigned short* bl = Bl + slot * BT;
        if (ph == 0) {
            load_lds_128(Ag + kof,                          al);
            load_lds_128(Ag + kof + (long)64 * lda,         al + 4096);
            load_lds_128(Bg + kof,                          bl);
        } else {
            load_lds_128(Ag + kof + (long)128 * lda,        al + 8192);
            load_lds_128(Ag + kof + (long)192 * lda,        al + 12288);
            load_lds_128(Bg + kof + (long)64 * ldb,         bl + 4096);
        }
    };

    // ---- fragment lane offsets (elems, lane-constant) ----
    // A frag (mf,kk): row R = wm*64+mf*16+l4, chunk g = kk*4+lh,
    //                 slot c = g ^ (R&7) = g ^ (lane&7)  (mf*16,wm*64 == 0 mod 8)
    const int aoff = (wm * 64 + l4) * 64;      // + mf*1024 + cs[kk]
    const int boff = (wn * 64 + l4) * 64;      // + nf*1024 + cs[kk]
    const int cs0  = ((0 + lh) ^ (lane & 7)) * 8;
    const int cs1  = ((4 + lh) ^ (lane & 7)) * 8;

    f32x4 acc[4][4] = {};

    // ---- prologue: stage tiles 0,1; drain tile 0 (6 loads stay in flight) ----
    stage(0, 0, 0); stage(0, 0, 1);
    stage(1, 1, 0); stage(1, 1, 1);
    asm volatile("s_waitcnt vmcnt(6)" ::: "memory");
    BAR();

    int sl = 0;
    for (int t = 0; t < NT; ++t) {
        const unsigned short* Ab = As + sl * AT + aoff;
        const unsigned short* Bb = Bs + sl * BT + boff;
        const int st = (sl >= 1) ? sl - 1 : 2;         // (sl+2)%3
        const bool pf = (t + 2 < NT);
        bf16x8 a[4], b[4];

        // ---------- phase 1 : kk = 0 ----------
#pragma unroll
        for (int mf = 0; mf < 4; ++mf) a[mf] = *(const bf16x8*)(Ab + mf * 1024 + cs0);
#pragma unroll
        for (int nf = 0; nf < 4; ++nf) b[nf] = *(const bf16x8*)(Bb + nf * 1024 + cs0);
        if (pf) stage(t + 2, st, 0);
        BAR();
        WAITL0();
        __builtin_amdgcn_s_setprio(1);
#pragma unroll
        for (int mf = 0; mf < 4; ++mf)
#pragma unroll
            for (int nf = 0; nf < 4; ++nf)
                acc[mf][nf] = __builtin_amdgcn_mfma_f32_16x16x32_bf16(
                    a[mf], b[nf], acc[mf][nf], 0, 0, 0);
        __builtin_amdgcn_s_setprio(0);

        // ---------- phase 2 : kk = 1 ----------
#pragma unroll
        for (int mf = 0; mf < 4; ++mf) a[mf] = *(const bf16x8*)(Ab + mf * 1024 + cs1);
#pragma unroll
        for (int nf = 0; nf < 4; ++nf) b[nf] = *(const bf16x8*)(Bb + nf * 1024 + cs1);
        if (pf) stage(t + 2, st, 1);
        BAR();
        WAITL0();
        __builtin_amdgcn_s_setprio(1);
#pragma unroll
        for (int mf = 0; mf < 4; ++mf)
#pragma unroll
            for (int nf = 0; nf < 4; ++nf)
                acc[mf][nf] = __builtin_amdgcn_mfma_f32_16x16x32_bf16(
                    a[mf], b[nf], acc[mf][nf], 0, 0, 0);
        __builtin_amdgcn_s_setprio(0);

        if (t < NT - 2) asm volatile("s_waitcnt vmcnt(6)" ::: "memory");
        else            asm volatile("s_waitcnt vmcnt(0)" ::: "memory");
        BAR();
        sl = (sl == 2) ? 0 : sl + 1;
    }

    // ---- epilogue ----
    // C/D 16x16x32: col = lane&15 (+nf*16), row = (lane>>4)*4 + reg (+mf*16)
    const int r0c = m0 + wm * 64 + lh * 4;
    const int c0c = n0 + wn * 64 + l4;

    if (MODE == 0) {
        if (n0 >= 2048) {
            // V columns -> vt[b][d][m] (+bias), packed 4-m ushort4 stores
#pragma unroll
            for (int nf = 0; nf < 4; ++nf) {
                const int d = c0c + nf * 16 - 2048;
                const float bias = b2[d];
#pragma unroll
                for (int mf = 0; mf < 4; ++mf) {
                    const int row = r0c + mf * 16;
                    const int bb = row >> 11;
                    const int mm = row & 2047;
                    ushort4 u;
                    u.x = f2bf(acc[mf][nf][0] + bias);
                    u.y = f2bf(acc[mf][nf][1] + bias);
                    u.z = f2bf(acc[mf][nf][2] + bias);
                    u.w = f2bf(acc[mf][nf][3] + bias);
                    *(ushort4*)(vt + ((long)bb * DIM + d) * SEQ + mm) = u;
                }
            }
        } else {
            unsigned short* C16 = (unsigned short*)Cv;
#pragma unroll
            for (int nf = 0; nf < 4; ++nf) {
                const int col = c0c + nf * 16;
                const float bias = (col >= 1024) ? b1[col - 1024] : b0[col];
#pragma unroll
                for (int mf = 0; mf < 4; ++mf)
#pragma unroll
                    for (int r = 0; r < 4; ++r)
                        C16[(long)(r0c + mf * 16 + r) * ldc + col] =
                            f2bf(acc[mf][nf][r] + bias);
            }
        }
    } else if (MODE == 1) {
        float* C = (float*)Cv + (long)z * sC;
        const float* ir = inv_rs + (long)z * SEQ;
#pragma unroll
        for (int mf = 0; mf < 4; ++mf) {
            const int row = r0c + mf * 16;
            const float4 inv4 = *(const float4*)(ir + row);
#pragma unroll
            for (int nf = 0; nf < 4; ++nf) {
                const int col = c0c + nf * 16;
                C[(long)(row + 0) * ldc + col] = acc[mf][nf][0] * inv4.x;
                C[(long)(row + 1) * ldc + col] = acc[mf][nf][1] * inv4.y;
                C[(long)(row + 2) * ldc + col] = acc[mf][nf][2] * inv4.z;
                C[(long)(row + 3) * ldc + col] = acc[mf][nf][3] * inv4.w;
            }
        }
    } else {  // MODE 2: P = exp(acc * alpha), bf16, unnormalized
        unsigned short* C16 = (unsigned short*)Cv + (long)z * sC;
#pragma unroll
        for (int nf = 0; nf < 4; ++nf) {
            const int col = c0c + nf * 16;
#pragma unroll
            for (int mf = 0; mf < 4; ++mf)
#pragma unroll
                for (int r = 0; r < 4; ++r)
                    C16[(long)(r0c + mf * 16 + r) * ldc + col] =
                        f2bf(__expf(acc[mf][nf][r] * alpha));
        }
    }
}

// ---------------------------------------------------------------------------
__global__ __launch_bounds__(256)
void cvt_x(const float* __restrict__ src, unsigned short* __restrict__ dst, int n4)
{
    int i = blockIdx.x * 256 + threadIdx.x;
    if (i < n4) {
        float4 f = ((const float4*)src)[i];
        ushort4 u;
        u.x = f2bf(f.x); u.y = f2bf(f.y); u.z = f2bf(f.z); u.w = f2bf(f.w);
        ((ushort4*)dst)[i] = u;
    }
}

__global__ __launch_bounds__(256)
void cvt_w3(const float* __restrict__ Wq, const float* __restrict__ Wk,
            const float* __restrict__ Wv, unsigned short* __restrict__ dst)
{
    const int sel = blockIdx.y;
    const float* src = (sel == 0) ? Wq : ((sel == 1) ? Wk : Wv);
    const int i = blockIdx.x * 256 + threadIdx.x;
    float4 f = ((const float4*)src)[i];
    ushort4 u;
    u.x = f2bf(f.x); u.y = f2bf(f.y); u.z = f2bf(f.z); u.w = f2bf(f.w);
    ((ushort4*)(dst + (long)sel * DIM * DIM))[i] = u;
}

// ---------------------------------------------------------------------------
// inv_rs[row] = 1 / sum(P[row][:]) over 2048 bf16 values. 1 wave per row.
// ---------------------------------------------------------------------------
__global__ __launch_bounds__(256)
void rowsum_inv(const unsigned short* __restrict__ P, float* __restrict__ inv_rs)
{
    const int row  = blockIdx.x * 4 + (threadIdx.x >> 6);
    const int lane = threadIdx.x & 63;
    const unsigned short* pr = P + (long)row * SEQ;

    float s = 0.f;
#pragma unroll
    for (int it = 0; it < 4; ++it) {
        uint4 u = *(const uint4*)(pr + (it * 64 + lane) * 8);
        s += bfu2f(u.x & 0xffffu) + __uint_as_float(u.x & 0xffff0000u);
        s += bfu2f(u.y & 0xffffu) + __uint_as_float(u.y & 0xffff0000u);
        s += bfu2f(u.z & 0xffffu) + __uint_as_float(u.z & 0xffff0000u);
        s += bfu2f(u.w & 0xffffu) + __uint_as_float(u.w & 0xffff0000u);
    }
    for (int off = 32; off > 0; off >>= 1)
        s += __shfl_xor(s, off);
    if (lane == 0) inv_rs[row] = 1.0f / s;
}

// ---------------------------------------------------------------------------
extern "C" void kernel_launch(void* const* d_in, const int* in_sizes, int n_in,
                              void* d_out, int out_size, void* d_ws, size_t ws_size,
                              hipStream_t stream)
{
    const float* x  = (const float*)d_in[0];
    const float* Wq = (const float*)d_in[1];
    const float* bq = (const float*)d_in[2];
    const float* Wk = (const float*)d_in[3];
    const float* bk = (const float*)d_in[4];
    const float* Wv = (const float*)d_in[5];
    const float* bv = (const float*)d_in[6];
    float* out = (float*)d_out;

    // Workspace layout (>=160MB + 32KB):
    //  [0,16MB):    xb bf16 [8192][1024]
    //  [16,22MB):   Wb bf16 [3][1024][1024]
    //  [64,112MB):  qkv bf16 [8192][3072]  (V cols never written; vt instead)
    //  [112,128MB): vt  bf16 [4][1024][2048]
    //  [128,160MB): P   bf16 [4][2048][2048]  (unnormalized exp)
    //  [160MB,+32KB): inv_rs fp32 [8192]
    char* ws = (char*)d_ws;
    unsigned short* xb   = (unsigned short*)ws;
    unsigned short* Wb   = (unsigned short*)(ws + 16u * 1024 * 1024);
    unsigned short* qkv  = (unsigned short*)(ws + 64u * 1024 * 1024);
    unsigned short* vt   = (unsigned short*)(ws + 112u * 1024 * 1024);
    unsigned short* P    = (unsigned short*)(ws + 128u * 1024 * 1024);
    float*          irs  = (float*)(ws + 160u * 1024 * 1024);

    const float scale = 0.03125f;   // 1/sqrt(1024)
    dim3 blk(256);
    dim3 blk512(512);

    // 1) converts
    cvt_x<<<NTOK * DIM / 4 / 256, blk, 0, stream>>>(x, xb, NTOK * DIM / 4);
    cvt_w3<<<dim3(DIM * DIM / 4 / 256, 3), blk, 0, stream>>>(Wq, Wk, Wv, Wb);

    // 2) fused QKV projection, 256x128 tiles -> 32*24 = 768 blocks (3 rounds)
    gemm256<0><<<dim3(NTOK / 256, NQKV / 128), blk512, 0, stream>>>(
        xb, Wb, qkv, bq, bk, bv, vt, nullptr,
        DIM, DIM, DIM, NQKV, 0, 0, 0, 1.0f);

    // 3) P[b] = exp(q[b].k[b]^T * scale), 256x128 tiles -> 8*16*4 = 512 blocks
    gemm256<2><<<dim3(SEQ / 256, SEQ / 128, 4), blk512, 0, stream>>>(
        qkv, qkv + 1024, P, nullptr, nullptr, nullptr, nullptr, nullptr,
        DIM, NQKV, NQKV, SEQ,
        (long)SEQ * NQKV, (long)SEQ * NQKV, (long)SEQ * SEQ, scale);

    // 4) inv_rs = 1 / rowsum(P)
    rowsum_inv<<<NTOK / 4, blk, 0, stream>>>(P, irs);

    // 5) out[b] = (P[b].vt[b]^T) * inv_rs, 256x128 tiles -> 8*8*4 = 256 blocks
    gemm256<1><<<dim3(SEQ / 256, DIM / 128, 4), blk512, 0, stream>>>(
        P, vt, out, nullptr, nullptr, nullptr, nullptr, irs,
        SEQ, SEQ, SEQ, DIM,
        (long)SEQ * SEQ, (long)DIM * SEQ, (long)SEQ * DIM, 1.0f);
}

// Round 3
// 244.026 us; speedup vs baseline: 1.1236x; 1.0488x over previous
//
#include <hip/hip_runtime.h>

#define SEQ  2048
#define DIM  1024
#define NTOK 8192   // 4*SEQ
#define NQKV 3072

typedef __attribute__((ext_vector_type(8))) __bf16 bf16x8;
typedef __attribute__((ext_vector_type(4))) float  f32x4;

__device__ __forceinline__ unsigned short f2bf(float f) {
    unsigned int u = __float_as_uint(f);
    u += 0x7fffu + ((u >> 16) & 1u);          // round-to-nearest-even
    return (unsigned short)(u >> 16);
}

__device__ __forceinline__ float bfu2f(unsigned int lo16) {
    return __uint_as_float(lo16 << 16);
}

__device__ __forceinline__ void load_lds_128(const unsigned short* g, unsigned short* l) {
    __builtin_amdgcn_global_load_lds(
        (const __attribute__((address_space(1))) void*)g,
        (__attribute__((address_space(3))) void*)l, 16, 0, 0);
}

#define BAR() asm volatile("s_barrier" ::: "memory")

// ---------------------------------------------------------------------------
// NT GEMM, bf16 MFMA 16x16x32. 256x128 block, BK=64, 8 waves as 4M x 2N
// (64x64 per wave, acc[4][4]).  3-slot LDS ring, distance-2 prefetch,
// counted vmcnt(6), ONE barrier per K-tile, and a register-level fragment
// double-buffer: each phase issues the NEXT phase's 8 ds_read_b128 (plain
// C++ loads -> compiler emits COUNTED lgkmcnt(8) before the MFMA cluster),
// then MFMAs the current registers.  Reads overlap MFMA within each wave.
//
// LDS rows are 128B (full bank period); chunk slot c of row r holds global
// chunk g = c ^ (r&7) -> fragment ds_read_b128 is 2-way (free), verified
// SQ_LDS_BANK_CONFLICT == 0.
//
// WAR invariant: manual lgkmcnt(0) immediately before the per-tile barrier
// ("all my reads done before passing"), so stages issued after a barrier
// (slot (t+2)%3) never race reads issued before it; the post-barrier
// read-ahead targets slot (t+1)%3 != (t+2)%3.  vmcnt(6) before the barrier
// drains tile t+1's 6 stage-loads (tile t+2's stay in flight).
//
// MODE 0: fused QKV epilogue (q,k bf16 + bias; v transposed into vt + bias)
// MODE 1: fp32 C = acc * inv_rs[row]   (normalized P.V output)
// MODE 2: bf16 C = exp(acc * alpha)    (unnormalized softmax numerator)
// ---------------------------------------------------------------------------
template <int MODE>
__global__ __launch_bounds__(512, 2)
void gemm256(const unsigned short* __restrict__ A, const unsigned short* __restrict__ B,
             void* __restrict__ Cv,
             const float* __restrict__ b0v, const float* __restrict__ b1v,
             const float* __restrict__ b2v, unsigned short* __restrict__ vt,
             const float* __restrict__ inv_rs,
             int K, int lda, int ldb, int ldc,
             long sA, long sB, long sC, float alpha)
{
    constexpr int AT = 256 * 64;               // elems per A slot (32 KB)
    constexpr int BT = 128 * 64;               // elems per B slot (16 KB)
    __shared__ __align__(16) unsigned short As[3 * AT];   // 96 KB
    __shared__ __align__(16) unsigned short Bs[3 * BT];   // 48 KB

    const int tid  = threadIdx.x;              // 512 threads = 8 waves
    const int wave = tid >> 6;
    const int lane = tid & 63;
    const int l4   = lane & 15;
    const int lh   = lane >> 4;
    const int wm   = wave >> 1;                // 0..3  (M quarter)
    const int wn   = wave & 1;                 // 0..1  (N half)

    const int m0 = blockIdx.x * 256;
    const int n0 = blockIdx.y * 128;
    const int z  = blockIdx.z;
    A += (long)z * sA;
    B += (long)z * sB;

    // ---- staging map: LDS linear pos s = tid + 512p -> row s>>3, slot s&7.
    // slot c holds global chunk g = c ^ (r&7); g is p-invariant (64p%8==0).
    const int r0 = tid >> 3;                   // 0..63
    const int gc = (tid & 7) ^ (r0 & 7);
    const unsigned short* Ag = A + (long)(m0 + r0) * lda + gc * 8;
    const unsigned short* Bg = B + (long)(n0 + r0) * ldb + gc * 8;
    unsigned short* Al = As + tid * 8;
    unsigned short* Bl = Bs + tid * 8;

    const int NT = K >> 6;                     // K-tiles of 64

    // phase 0: A rows 0-127 + B rows 0-63;  phase 1: A rows 128-255 + B 64-127
    auto stage = [&](int t, int slot, int ph) {
        const long kof = (long)t * 64;
        unsigned short* al = Al + slot * AT;
        unsigned short* bl = Bl + slot * BT;
        if (ph == 0) {
            load_lds_128(Ag + kof,                          al);
            load_lds_128(Ag + kof + (long)64 * lda,         al + 4096);
            load_lds_128(Bg + kof,                          bl);
        } else {
            load_lds_128(Ag + kof + (long)128 * lda,        al + 8192);
            load_lds_128(Ag + kof + (long)192 * lda,        al + 12288);
            load_lds_128(Bg + kof + (long)64 * ldb,         bl + 4096);
        }
    };

    // ---- fragment lane offsets (elems, lane-constant) ----
    // A frag (mf,kk): row R = wm*64+mf*16+l4, chunk g = kk*4+lh,
    //                 slot c = g ^ (R&7) = g ^ (lane&7)
    const int aoff = (wm * 64 + l4) * 64;      // + mf*1024 + cs[kk]
    const int boff = (wn * 64 + l4) * 64;      // + nf*1024 + cs[kk]
    const int cs0  = ((0 + lh) ^ (lane & 7)) * 8;
    const int cs1  = ((4 + lh) ^ (lane & 7)) * 8;

    f32x4 acc[4][4] = {};
    bf16x8 a0[4], b0[4], a1[4], b1[4];

    auto ldfrag = [&](bf16x8 (&a)[4], bf16x8 (&b)[4],
                      const unsigned short* Ab, const unsigned short* Bb, int cs) {
#pragma unroll
        for (int mf = 0; mf < 4; ++mf) a[mf] = *(const bf16x8*)(Ab + mf * 1024 + cs);
#pragma unroll
        for (int nf = 0; nf < 4; ++nf) b[nf] = *(const bf16x8*)(Bb + nf * 1024 + cs);
    };
    auto mfma16 = [&](bf16x8 (&a)[4], bf16x8 (&b)[4]) {
        __builtin_amdgcn_s_setprio(1);
#pragma unroll
        for (int mf = 0; mf < 4; ++mf)
#pragma unroll
            for (int nf = 0; nf < 4; ++nf)
                acc[mf][nf] = __builtin_amdgcn_mfma_f32_16x16x32_bf16(
                    a[mf], b[nf], acc[mf][nf], 0, 0, 0);
        __builtin_amdgcn_s_setprio(0);
    };

    // ---- prologue: stage tiles 0,1; drain tile 0 (stage(1) stays in flight) ----
    stage(0, 0, 0); stage(0, 0, 1);
    stage(1, 1, 0); stage(1, 1, 1);
    asm volatile("s_waitcnt vmcnt(6)" ::: "memory");
    BAR();
    ldfrag(a0, b0, As + aoff, Bs + boff, cs0);   // tile 0, kk=0

    int sl = 0;
    for (int t = 0; t < NT; ++t) {
        const unsigned short* Ab = As + sl * AT + aoff;
        const unsigned short* Bb = Bs + sl * BT + boff;
        const int st  = (sl >= 1) ? sl - 1 : 2;        // (sl+2)%3
        const int nsl = (sl == 2) ? 0 : sl + 1;

        // ---------- phase A: issue rd(t,kk1), stage, MFMA on (t,kk0) ----------
        ldfrag(a1, b1, Ab, Bb, cs1);
        if (t + 2 < NT) stage(t + 2, st, 0);
        mfma16(a0, b0);                 // compiler waits lgkmcnt(8): a1/b1 in flight

        // ---------- phase B: stage, drain+barrier, rd(t+1,kk0), MFMA (t,kk1) ----
        if (t + 2 < NT) stage(t + 2, st, 1);
        asm volatile("s_waitcnt lgkmcnt(0)" ::: "memory");   // WAR invariant
        if (t < NT - 2) asm volatile("s_waitcnt vmcnt(6)" ::: "memory");
        else            asm volatile("s_waitcnt vmcnt(0)" ::: "memory");
        BAR();
        if (t + 1 < NT)
            ldfrag(a0, b0, As + nsl * AT + aoff, Bs + nsl * BT + boff, cs0);
        mfma16(a1, b1);                 // a1/b1 already drained -> no wait; a0/b0 in flight
        sl = nsl;
    }

    // ---- epilogue ----
    // C/D 16x16x32: col = lane&15 (+nf*16), row = (lane>>4)*4 + reg (+mf*16)
    const int r0c = m0 + wm * 64 + lh * 4;
    const int c0c = n0 + wn * 64 + l4;

    if (MODE == 0) {
        if (n0 >= 2048) {
            // V columns -> vt[b][d][m] (+bias), packed 4-m ushort4 stores
#pragma unroll
            for (int nf = 0; nf < 4; ++nf) {
                const int d = c0c + nf * 16 - 2048;
                const float bias = b2v[d];
#pragma unroll
                for (int mf = 0; mf < 4; ++mf) {
                    const int row = r0c + mf * 16;
                    const int bb = row >> 11;
                    const int mm = row & 2047;
                    ushort4 u;
                    u.x = f2bf(acc[mf][nf][0] + bias);
                    u.y = f2bf(acc[mf][nf][1] + bias);
                    u.z = f2bf(acc[mf][nf][2] + bias);
                    u.w = f2bf(acc[mf][nf][3] + bias);
                    *(ushort4*)(vt + ((long)bb * DIM + d) * SEQ + mm) = u;
                }
            }
        } else {
            unsigned short* C16 = (unsigned short*)Cv;
#pragma unroll
            for (int nf = 0; nf < 4; ++nf) {
                const int col = c0c + nf * 16;
                const float bias = (col >= 1024) ? b1v[col - 1024] : b0v[col];
#pragma unroll
                for (int mf = 0; mf < 4; ++mf)
#pragma unroll
                    for (int r = 0; r < 4; ++r)
                        C16[(long)(r0c + mf * 16 + r) * ldc + col] =
                            f2bf(acc[mf][nf][r] + bias);
            }
        }
    } else if (MODE == 1) {
        float* C = (float*)Cv + (long)z * sC;
        const float* ir = inv_rs + (long)z * SEQ;
#pragma unroll
        for (int mf = 0; mf < 4; ++mf) {
            const int row = r0c + mf * 16;
            const float4 inv4 = *(const float4*)(ir + row);
#pragma unroll
            for (int nf = 0; nf < 4; ++nf) {
                const int col = c0c + nf * 16;
                C[(long)(row + 0) * ldc + col] = acc[mf][nf][0] * inv4.x;
                C[(long)(row + 1) * ldc + col] = acc[mf][nf][1] * inv4.y;
                C[(long)(row + 2) * ldc + col] = acc[mf][nf][2] * inv4.z;
                C[(long)(row + 3) * ldc + col] = acc[mf][nf][3] * inv4.w;
            }
        }
    } else {  // MODE 2: P = exp(acc * alpha), bf16, unnormalized
        unsigned short* C16 = (unsigned short*)Cv + (long)z * sC;
#pragma unroll
        for (int nf = 0; nf < 4; ++nf) {
            const int col = c0c + nf * 16;
#pragma unroll
            for (int mf = 0; mf < 4; ++mf)
#pragma unroll
                for (int r = 0; r < 4; ++r)
                    C16[(long)(r0c + mf * 16 + r) * ldc + col] =
                        f2bf(__expf(acc[mf][nf][r] * alpha));
        }
    }
}

// ---------------------------------------------------------------------------
__global__ __launch_bounds__(256)
void cvt_x(const float* __restrict__ src, unsigned short* __restrict__ dst, int n4)
{
    int i = blockIdx.x * 256 + threadIdx.x;
    if (i < n4) {
        float4 f = ((const float4*)src)[i];
        ushort4 u;
        u.x = f2bf(f.x); u.y = f2bf(f.y); u.z = f2bf(f.z); u.w = f2bf(f.w);
        ((ushort4*)dst)[i] = u;
    }
}

__global__ __launch_bounds__(256)
void cvt_w3(const float* __restrict__ Wq, const float* __restrict__ Wk,
            const float* __restrict__ Wv, unsigned short* __restrict__ dst)
{
    const int sel = blockIdx.y;
    const float* src = (sel == 0) ? Wq : ((sel == 1) ? Wk : Wv);
    const int i = blockIdx.x * 256 + threadIdx.x;
    float4 f = ((const float4*)src)[i];
    ushort4 u;
    u.x = f2bf(f.x); u.y = f2bf(f.y); u.z = f2bf(f.z); u.w = f2bf(f.w);
    ((ushort4*)(dst + (long)sel * DIM * DIM))[i] = u;
}

// ---------------------------------------------------------------------------
// inv_rs[row] = 1 / sum(P[row][:]) over 2048 bf16 values. 1 wave per row.
// ---------------------------------------------------------------------------
__global__ __launch_bounds__(256)
void rowsum_inv(const unsigned short* __restrict__ P, float* __restrict__ inv_rs)
{
    const int row  = blockIdx.x * 4 + (threadIdx.x >> 6);
    const int lane = threadIdx.x & 63;
    const unsigned short* pr = P + (long)row * SEQ;

    float s = 0.f;
#pragma unroll
    for (int it = 0; it < 4; ++it) {
        uint4 u = *(const uint4*)(pr + (it * 64 + lane) * 8);
        s += bfu2f(u.x & 0xffffu) + __uint_as_float(u.x & 0xffff0000u);
        s += bfu2f(u.y & 0xffffu) + __uint_as_float(u.y & 0xffff0000u);
        s += bfu2f(u.z & 0xffffu) + __uint_as_float(u.z & 0xffff0000u);
        s += bfu2f(u.w & 0xffffu) + __uint_as_float(u.w & 0xffff0000u);
    }
    for (int off = 32; off > 0; off >>= 1)
        s += __shfl_xor(s, off);
    if (lane == 0) inv_rs[row] = 1.0f / s;
}

// ---------------------------------------------------------------------------
extern "C" void kernel_launch(void* const* d_in, const int* in_sizes, int n_in,
                              void* d_out, int out_size, void* d_ws, size_t ws_size,
                              hipStream_t stream)
{
    const float* x  = (const float*)d_in[0];
    const float* Wq = (const float*)d_in[1];
    const float* bq = (const float*)d_in[2];
    const float* Wk = (const float*)d_in[3];
    const float* bk = (const float*)d_in[4];
    const float* Wv = (const float*)d_in[5];
    const float* bv = (const float*)d_in[6];
    float* out = (float*)d_out;

    // Workspace layout (>=160MB + 32KB):
    //  [0,16MB):    xb bf16 [8192][1024]
    //  [16,22MB):   Wb bf16 [3][1024][1024]
    //  [64,112MB):  qkv bf16 [8192][3072]  (V cols never written; vt instead)
    //  [112,128MB): vt  bf16 [4][1024][2048]
    //  [128,160MB): P   bf16 [4][2048][2048]  (unnormalized exp)
    //  [160MB,+32KB): inv_rs fp32 [8192]
    char* ws = (char*)d_ws;
    unsigned short* xb   = (unsigned short*)ws;
    unsigned short* Wb   = (unsigned short*)(ws + 16u * 1024 * 1024);
    unsigned short* qkv  = (unsigned short*)(ws + 64u * 1024 * 1024);
    unsigned short* vt   = (unsigned short*)(ws + 112u * 1024 * 1024);
    unsigned short* P    = (unsigned short*)(ws + 128u * 1024 * 1024);
    float*          irs  = (float*)(ws + 160u * 1024 * 1024);

    const float scale = 0.03125f;   // 1/sqrt(1024)
    dim3 blk(256);
    dim3 blk512(512);

    // 1) converts
    cvt_x<<<NTOK * DIM / 4 / 256, blk, 0, stream>>>(x, xb, NTOK * DIM / 4);
    cvt_w3<<<dim3(DIM * DIM / 4 / 256, 3), blk, 0, stream>>>(Wq, Wk, Wv, Wb);

    // 2) fused QKV projection, 256x128 tiles -> 32*24 = 768 blocks (3 rounds)
    gemm256<0><<<dim3(NTOK / 256, NQKV / 128), blk512, 0, stream>>>(
        xb, Wb, qkv, bq, bk, bv, vt, nullptr,
        DIM, DIM, DIM, NQKV, 0, 0, 0, 1.0f);

    // 3) P[b] = exp(q[b].k[b]^T * scale), 256x128 tiles -> 8*16*4 = 512 blocks
    gemm256<2><<<dim3(SEQ / 256, SEQ / 128, 4), blk512, 0, stream>>>(
        qkv, qkv + 1024, P, nullptr, nullptr, nullptr, nullptr, nullptr,
        DIM, NQKV, NQKV, SEQ,
        (long)SEQ * NQKV, (long)SEQ * NQKV, (long)SEQ * SEQ, scale);

    // 4) inv_rs = 1 / rowsum(P)
    rowsum_inv<<<NTOK / 4, blk, 0, stream>>>(P, irs);

    // 5) out[b] = (P[b].vt[b]^T) * inv_rs, 256x128 tiles -> 8*8*4 = 256 blocks
    gemm256<1><<<dim3(SEQ / 256, DIM / 128, 4), blk512, 0, stream>>>(
        P, vt, out, nullptr, nullptr, nullptr, nullptr, irs,
        SEQ, SEQ, SEQ, DIM,
        (long)SEQ * SEQ, (long)DIM * SEQ, (long)SEQ * DIM, 1.0f);
}